// Round 14
// baseline (173.617 us; speedup 1.0000x reference)
//
#include <hip/hip_runtime.h>
#include <hip/hip_bf16.h>

// ---------------------------------------------------------------------------
// CGNN: 2 layers of { m = h[src]*e ; s = segment_mean(m,dst) ;
//                     [h, h_N] @ W + b (+ relu on layer 1) }
// Round 13: multisplit grid starvation fix — EPT 8->4 (EPB 4096) doubles
// blocks to 391 (~76% machine wave occupancy). Slightly more write amp
// (runs ~2.6 edges), far less exposed latency.
//   - padded per-bucket windows (init_cursor / multisplit / bucket_sort)
//   - agg v6: 2 nodes per wave, 8 edges/node in flight, byte-offset records
//   - linear_lds kernels (r9), bf16 gather tables (r6)
// ---------------------------------------------------------------------------

#define F 64
#define NBMAX 2048          // bucket arrays sized for up to 2048 buckets
#define EPT 4               // edges per thread in multisplit
#define TPB 1024            // threads per block in multisplit
#define EPB (EPT * TPB)     // edges per block = 4096
#define PADBKT 1280         // padded window per bucket (mean 1024, +8 sigma)

__global__ __launch_bounds__(256) void init_cursor_kernel(
    int* __restrict__ bcursor, int nb)
{
    const int i = blockIdx.x * 256 + threadIdx.x;
    if (i < nb) bcursor[i] = i * PADBKT;
}

// Block-local multisplit into padded per-bucket windows: rank 4096 edges in
// LDS, reserve per-bucket ranges with one global atomic per non-empty bucket,
// write dense runs. rec.x = (local_dst << 20) | src, rec.y = bits(edge_feat).
__global__ __launch_bounds__(TPB) void multisplit_kernel(
    const int* __restrict__ src, const int* __restrict__ dst,
    const float* __restrict__ ef, int* __restrict__ bcursor,
    int2* __restrict__ brec, int n_edges, int nb)
{
    __shared__ int lcnt[NBMAX];
    __shared__ int lbase[NBMAX];
    const int tid = threadIdx.x;
    for (int i = tid; i < nb; i += TPB) lcnt[i] = 0;
    __syncthreads();

    const int e0 = blockIdx.x * EPB + tid;
    int d[EPT], rk[EPT];
#pragma unroll
    for (int k = 0; k < EPT; ++k) {
        const int e = e0 + k * TPB;
        const int dd = (e < n_edges) ? dst[e] : -1;
        d[k]  = dd;
        rk[k] = (dd >= 0) ? atomicAdd(&lcnt[dd >> 6], 1) : 0;
    }
    __syncthreads();
    for (int i = tid; i < nb; i += TPB) {
        const int c = lcnt[i];
        lbase[i] = c ? atomicAdd(&bcursor[i], c) : 0;
    }
    __syncthreads();
#pragma unroll
    for (int k = 0; k < EPT; ++k) {
        const int e = e0 + k * TPB;
        if (e < n_edges) {
            const int dd  = d[k];
            const int bkt = dd >> 6;
            const int pos = lbase[bkt] + rk[k];
            if (pos < (bkt + 1) * PADBKT)   // overflow guard (never with data)
                brec[pos] = make_int2(((dd & 63) << 20) | src[e],
                                      __float_as_int(ef[e]));
        }
    }
}

// Block per bucket: stage window records in LDS, 64-counter histogram + wave
// scan, compact back at exact per-node positions (front of window). Final
// records carry PRE-SCALED byte offsets (src*128). Emits off2/end2/invdeg.
__global__ __launch_bounds__(256) void bucket_sort_kernel(
    int2* __restrict__ brec, const int* __restrict__ bcursor,
    int* __restrict__ off2, int* __restrict__ end2,
    float* __restrict__ invdeg, int n_nodes)
{
    __shared__ int2 stage[PADBKT];
    __shared__ int  lcnt[64];
    __shared__ int  lcur[64];

    const int b   = blockIdx.x;
    const int tid = threadIdx.x;
    const int w0  = b * PADBKT;
    int cnt = bcursor[b] - w0;
    if (cnt > PADBKT) cnt = PADBKT;

    if (tid < 64) lcnt[tid] = 0;
    __syncthreads();

    for (int i = tid; i < cnt; i += 256) {
        const int2 r = brec[w0 + i];
        stage[i] = r;
        atomicAdd(&lcnt[r.x >> 20], 1);
    }
    __syncthreads();

    if (tid < 64) {
        const int c = lcnt[tid];
        int v = c;
        for (int d = 1; d < 64; d <<= 1) {
            int t = __shfl_up(v, d, 64);
            if (tid >= d) v += t;
        }
        const int excl = v - c;
        lcur[tid] = excl;
        const int node = (b << 6) + tid;
        if (node < n_nodes) {
            off2[node]   = w0 + excl;
            end2[node]   = w0 + excl + c;
            invdeg[node] = 1.0f / fmaxf((float)c, 1.0f);
        }
    }
    __syncthreads();

    for (int i = tid; i < cnt; i += 256) {
        const int2 r   = stage[i];
        const int  pos = atomicAdd(&lcur[r.x >> 20], 1);
        brec[w0 + pos] = make_int2((r.x & 0xFFFFF) << 7, r.y);  // byte offset
    }
}

__device__ __forceinline__ unsigned bf16_rne(float f)
{
    unsigned u = __float_as_uint(f);
    return (u + 0x7FFFu + ((u >> 16) & 1u)) >> 16;
}

// RNE-convert fp32 array to packed bf16 (8 elems / thread).
__global__ __launch_bounds__(256) void f32_to_bf16_kernel(
    const float* __restrict__ x, unsigned short* __restrict__ y, int n8)
{
    const int i = blockIdx.x * 256 + threadIdx.x;
    if (i >= n8) return;
    const float4 a = ((const float4*)x)[2 * i];
    const float4 b = ((const float4*)x)[2 * i + 1];
    uint4 o;
    o.x = bf16_rne(a.x) | (bf16_rne(a.y) << 16);
    o.y = bf16_rne(a.z) | (bf16_rne(a.w) << 16);
    o.z = bf16_rne(b.x) | (bf16_rne(b.y) << 16);
    o.w = bf16_rne(b.z) | (bf16_rne(b.w) << 16);
    ((uint4*)y)[i] = o;
}

// TWO nodes per wave: n = lane>>5 selects the node, within 32 lanes
// g = 0..3 edge slots x q = 0..7 feature octets. 2 slots unrolled
// (A = base+g, B = base+4+g) -> 8 edges/node in flight. rec.x = byte offset.
// Reduce over g: 2 shfl_xor stages (m=8,16) shared by both nodes.
__global__ __launch_bounds__(256) void agg_kernel(
    const unsigned short* __restrict__ hb, const int2* __restrict__ rec,
    const int* __restrict__ off, const int* __restrict__ end,
    const float* __restrict__ invdeg, float* __restrict__ s, int n_nodes)
{
    const int wid  = (blockIdx.x * 256 + threadIdx.x) >> 6;
    const int lane = threadIdx.x & 63;
    const int n    = lane >> 5;        // node select within wave
    const int r    = lane & 31;
    const int g    = r >> 3;           // 0..3 edge slot
    const int q    = r & 7;            // 0..7 feature octet

    const int  node   = wid * 2 + n;
    const bool active = node < n_nodes;
    const int  e0 = active ? off[node] : 0;
    const int  e1 = active ? end[node] : 0;

    const char* __restrict__ hq = (const char*)hb + q * 16;

    float4 aA0 = make_float4(0.f, 0.f, 0.f, 0.f);
    float4 aA1 = make_float4(0.f, 0.f, 0.f, 0.f);
    float4 aB0 = make_float4(0.f, 0.f, 0.f, 0.f);
    float4 aB1 = make_float4(0.f, 0.f, 0.f, 0.f);

    for (int base = e0; base < e1; base += 8) {
        const int  eA = base + g;
        const int  eB = base + 4 + g;
        const bool vA = eA < e1;
        const bool vB = eB < e1;
        const int2 rA = rec[vA ? eA : e0];
        const int2 rB = rec[vB ? eB : e0];
        const float evA = vA ? __int_as_float(rA.y) : 0.f;
        const float evB = vB ? __int_as_float(rB.y) : 0.f;
        const uint4 xA = *(const uint4*)(hq + rA.x);
        const uint4 xB = *(const uint4*)(hq + rB.x);

        aA0.x = fmaf(__uint_as_float(xA.x << 16),         evA, aA0.x);
        aA0.y = fmaf(__uint_as_float(xA.x & 0xFFFF0000u), evA, aA0.y);
        aA0.z = fmaf(__uint_as_float(xA.y << 16),         evA, aA0.z);
        aA0.w = fmaf(__uint_as_float(xA.y & 0xFFFF0000u), evA, aA0.w);
        aA1.x = fmaf(__uint_as_float(xA.z << 16),         evA, aA1.x);
        aA1.y = fmaf(__uint_as_float(xA.z & 0xFFFF0000u), evA, aA1.y);
        aA1.z = fmaf(__uint_as_float(xA.w << 16),         evA, aA1.z);
        aA1.w = fmaf(__uint_as_float(xA.w & 0xFFFF0000u), evA, aA1.w);

        aB0.x = fmaf(__uint_as_float(xB.x << 16),         evB, aB0.x);
        aB0.y = fmaf(__uint_as_float(xB.x & 0xFFFF0000u), evB, aB0.y);
        aB0.z = fmaf(__uint_as_float(xB.y << 16),         evB, aB0.z);
        aB0.w = fmaf(__uint_as_float(xB.y & 0xFFFF0000u), evB, aB0.w);
        aB1.x = fmaf(__uint_as_float(xB.z << 16),         evB, aB1.x);
        aB1.y = fmaf(__uint_as_float(xB.z & 0xFFFF0000u), evB, aB1.y);
        aB1.z = fmaf(__uint_as_float(xB.w << 16),         evB, aB1.z);
        aB1.w = fmaf(__uint_as_float(xB.w & 0xFFFF0000u), evB, aB1.w);
    }

    float4 a0 = make_float4(aA0.x + aB0.x, aA0.y + aB0.y,
                            aA0.z + aB0.z, aA0.w + aB0.w);
    float4 a1 = make_float4(aA1.x + aB1.x, aA1.y + aB1.y,
                            aA1.z + aB1.z, aA1.w + aB1.w);

    // reduce across g (m = 8, 16) — stays within each 32-lane node half
#pragma unroll
    for (int m = 8; m <= 16; m <<= 1) {
        a0.x += __shfl_xor(a0.x, m); a0.y += __shfl_xor(a0.y, m);
        a0.z += __shfl_xor(a0.z, m); a0.w += __shfl_xor(a0.w, m);
        a1.x += __shfl_xor(a1.x, m); a1.y += __shfl_xor(a1.y, m);
        a1.z += __shfl_xor(a1.z, m); a1.w += __shfl_xor(a1.w, m);
    }

    if (g == 0 && active) {
        const float id = invdeg[node];
        float* __restrict__ srow = s + (size_t)node * F + q * 8;
        *(float4*)srow = make_float4(a0.x * id, a0.y * id, a0.z * id, a0.w * id);
        *(float4*)(srow + 4) = make_float4(a1.x * id, a1.y * id, a1.z * id, a1.w * id);
    }
}

// Block = 64 nodes x 4 waves. Stage x = [h|s] rows into LDS with coalesced
// loads (h from fp32 or bf16 shadow per IN_BF16), s always fp32. Wave wv
// computes output cols [wv*JT, ...) for all 64 nodes (lane = node), reading
// x from LDS (ds_read_b128) and W via wave-uniform s_load.
// OUT_BF16: write only the bf16 shadow row (next layer's gather + lin input).
template <int OUT, bool RELU, bool IN_BF16, bool OUT_BF16>
__global__ __launch_bounds__(256) void linear_lds_kernel(
    const float* __restrict__ hin_f, const unsigned short* __restrict__ hin_b,
    const float* __restrict__ s,
    const float* __restrict__ W, const float* __restrict__ b,
    float* __restrict__ out, unsigned short* __restrict__ hb_out, int n_nodes)
{
    constexpr int JT  = OUT / 4;   // j-tile per wave: 16 (lin1) / 8 (lin2)
    constexpr int STR = 132;       // row stride in floats (128 + 4, 16B-aligned)
    __shared__ float xin[64 * STR];

    const int tid   = threadIdx.x;
    const int node0 = blockIdx.x * 64;

    if constexpr (IN_BF16) {
        for (int i = tid; i < 512; i += 256) {
            const int ln = i >> 3, c8 = i & 7;
            const int node = node0 + ln;
            uint4 v = make_uint4(0u, 0u, 0u, 0u);
            if (node < n_nodes)
                v = *(const uint4*)&hin_b[(size_t)node * F + c8 * 8];
            float4 lo = make_float4(__uint_as_float(v.x << 16),
                                    __uint_as_float(v.x & 0xFFFF0000u),
                                    __uint_as_float(v.y << 16),
                                    __uint_as_float(v.y & 0xFFFF0000u));
            float4 hi = make_float4(__uint_as_float(v.z << 16),
                                    __uint_as_float(v.z & 0xFFFF0000u),
                                    __uint_as_float(v.w << 16),
                                    __uint_as_float(v.w & 0xFFFF0000u));
            *(float4*)&xin[ln * STR + c8 * 8]     = lo;
            *(float4*)&xin[ln * STR + c8 * 8 + 4] = hi;
        }
    } else {
        for (int i = tid; i < 1024; i += 256) {
            const int ln = i >> 4, c4 = i & 15;
            const int node = node0 + ln;
            float4 v = make_float4(0.f, 0.f, 0.f, 0.f);
            if (node < n_nodes)
                v = *(const float4*)&hin_f[(size_t)node * F + c4 * 4];
            *(float4*)&xin[ln * STR + c4 * 4] = v;
        }
    }
    for (int i = tid; i < 1024; i += 256) {
        const int ln = i >> 4, c4 = i & 15;
        const int node = node0 + ln;
        float4 v = make_float4(0.f, 0.f, 0.f, 0.f);
        if (node < n_nodes) v = *(const float4*)&s[(size_t)node * F + c4 * 4];
        *(float4*)&xin[ln * STR + F + c4 * 4] = v;
    }
    __syncthreads();

    const int lane = tid & 63;
    const int j0   = __builtin_amdgcn_readfirstlane((tid >> 6) * JT);

    float acc[JT];
#pragma unroll
    for (int j = 0; j < JT; ++j) acc[j] = b[j0 + j];

    const float* __restrict__ xrow = &xin[lane * STR];
#pragma unroll 2
    for (int k4 = 0; k4 < 32; ++k4) {
        const float4 xv = *(const float4*)&xrow[k4 * 4];
#pragma unroll
        for (int kk = 0; kk < 4; ++kk) {
            const int   k  = k4 * 4 + kk;
            const float xk = ((const float*)&xv)[kk];
#pragma unroll
            for (int j = 0; j < JT; ++j)
                acc[j] = fmaf(xk, W[k * OUT + j0 + j], acc[j]);
        }
    }

    const int node = node0 + lane;
    if (node < n_nodes) {
#pragma unroll
        for (int j = 0; j < JT; ++j) {
            float v = acc[j];
            if (RELU) v = fmaxf(v, 0.f);
            acc[j] = v;
        }
        if constexpr (OUT_BF16) {
            unsigned* __restrict__ hw =
                (unsigned*)(hb_out + (size_t)node * OUT + j0);
#pragma unroll
            for (int j = 0; j < JT; j += 2)
                hw[j >> 1] = bf16_rne(acc[j]) | (bf16_rne(acc[j + 1]) << 16);
        } else {
#pragma unroll
            for (int j = 0; j < JT; ++j)
                out[(size_t)node * OUT + j0 + j] = acc[j];
        }
    }
}

extern "C" void kernel_launch(void* const* d_in, const int* in_sizes, int n_in,
                              void* d_out, int out_size, void* d_ws, size_t ws_size,
                              hipStream_t stream)
{
    const float* in_feat   = (const float*)d_in[0];
    const float* edge_feat = (const float*)d_in[1];
    const int*   src       = (const int*)d_in[2];
    const int*   dst       = (const int*)d_in[3];
    const float* W1        = (const float*)d_in[4];
    const float* b1        = (const float*)d_in[5];
    const float* W2        = (const float*)d_in[6];
    const float* b2        = (const float*)d_in[7];
    float*       out       = (float*)d_out;

    const int n_nodes = in_sizes[0] / F;
    const int n_edges = in_sizes[2];
    const int nb      = (n_nodes + 63) >> 6;  // 64-node buckets

    // workspace layout (4-byte units)
    const int S = 100352;  // >= n_nodes+1, multiple of 256
    int*   wsi     = (int*)d_ws;
    int*   bcursor = wsi;                                 // [nb]
    int*   off2    = wsi + 2048;                          // [n_nodes]
    int*   end2    = wsi + 2048 + S;                      // [n_nodes]
    float* invdeg  = (float*)(wsi + 2048 + 2 * S);        // [n_nodes]
    int2*  brec    = (int2*)(wsi + 2048 + 3 * S);         // [nb * PADBKT]
    float* s       = (float*)(brec + (size_t)nb * PADBKT);
    unsigned short* hb = (unsigned short*)(s + (size_t)n_nodes * F);

    const int egrid = (n_edges + EPB - 1) / EPB;
    init_cursor_kernel<<<(nb + 255) / 256, 256, 0, stream>>>(bcursor, nb);
    multisplit_kernel<<<egrid, TPB, 0, stream>>>(src, dst, edge_feat,
                                                 bcursor, brec, n_edges, nb);
    bucket_sort_kernel<<<nb, 256, 0, stream>>>(brec, bcursor, off2, end2,
                                               invdeg, n_nodes);

    const int n8    = (n_nodes * F) >> 3;
    const int cgrid = (n8 + 255) / 256;
    const int agrid = (n_nodes + 7) / 8;     // 2 nodes/wave, 4 waves/block
    const int lgrid = (n_nodes + 63) / 64;

    // ---- layer 1 ----
    f32_to_bf16_kernel<<<cgrid, 256, 0, stream>>>(in_feat, hb, n8);
    agg_kernel<<<agrid, 256, 0, stream>>>(hb, brec, off2, end2, invdeg, s, n_nodes);
    linear_lds_kernel<64, true, false, true><<<lgrid, 256, 0, stream>>>(
        in_feat, nullptr, s, W1, b1, nullptr, hb, n_nodes);

    // ---- layer 2 ----
    agg_kernel<<<agrid, 256, 0, stream>>>(hb, brec, off2, end2, invdeg, s, n_nodes);
    linear_lds_kernel<32, false, true, false><<<lgrid, 256, 0, stream>>>(
        nullptr, hb, s, W2, b2, out, nullptr, n_nodes);
}

// Round 15
// 166.978 us; speedup vs baseline: 1.0398x; 1.0398x over previous
//
#include <hip/hip_runtime.h>
#include <hip/hip_bf16.h>

// ---------------------------------------------------------------------------
// CGNN: 2 layers of { m = h[src]*e ; s = segment_mean(m,dst) ;
//                     [h, h_N] @ W + b (+ relu on layer 1) }
// Round 14: SUPERBUCKETS (256 nodes) — cut multisplit's global-atomic fan-out.
//   - multisplit: EPB 8192, lcnt/lbase[512]; per-block global atomics ~391
//     (was ~1560); runs ~21 edges -> write amp ~1.3x
//   - bucket_sort v3: block per superbucket (512 thr), stage <=4864 recs in
//     LDS, 256-counter histogram + 2-level scan, in-place compact; emits
//     off2/end2/invdeg; records carry PRE-SCALED byte offsets (src*128)
//   - agg v6 (2 nodes/wave), linear_lds (r9), bf16 tables (r6) unchanged
// ---------------------------------------------------------------------------

#define F 64
#define EPT 8               // edges per thread in multisplit
#define TPB 1024            // threads per block in multisplit
#define EPB (EPT * TPB)     // edges per block = 8192
#define SBSHIFT 8           // 256 nodes per superbucket
#define SBSZ 256
#define NSBMAX 512
#define PADSB 4864          // padded window per superbucket (mean 4092, +12σ)

__global__ __launch_bounds__(256) void init_cursor_kernel(
    int* __restrict__ bcursor, int nsb)
{
    const int i = blockIdx.x * 256 + threadIdx.x;
    if (i < nsb) bcursor[i] = i * PADSB;
}

// Block-local multisplit into padded per-superbucket windows.
// rec.x = (local_dst << 17) | src  (local 8 bits, src 17 bits)
__global__ __launch_bounds__(TPB) void multisplit_kernel(
    const int* __restrict__ src, const int* __restrict__ dst,
    const float* __restrict__ ef, int* __restrict__ bcursor,
    int2* __restrict__ brec, int n_edges, int nsb)
{
    __shared__ int lcnt[NSBMAX];
    __shared__ int lbase[NSBMAX];
    const int tid = threadIdx.x;
    for (int i = tid; i < nsb; i += TPB) lcnt[i] = 0;
    __syncthreads();

    const int e0 = blockIdx.x * EPB + tid;
    int d[EPT], rk[EPT];
#pragma unroll
    for (int k = 0; k < EPT; ++k) {
        const int e = e0 + k * TPB;
        const int dd = (e < n_edges) ? dst[e] : -1;
        d[k]  = dd;
        rk[k] = (dd >= 0) ? atomicAdd(&lcnt[dd >> SBSHIFT], 1) : 0;
    }
    __syncthreads();
    for (int i = tid; i < nsb; i += TPB) {
        const int c = lcnt[i];
        lbase[i] = c ? atomicAdd(&bcursor[i], c) : 0;
    }
    __syncthreads();
#pragma unroll
    for (int k = 0; k < EPT; ++k) {
        const int e = e0 + k * TPB;
        if (e < n_edges) {
            const int dd  = d[k];
            const int bkt = dd >> SBSHIFT;
            const int pos = lbase[bkt] + rk[k];
            if (pos < (bkt + 1) * PADSB)   // overflow guard (never with data)
                brec[pos] = make_int2(((dd & (SBSZ - 1)) << 17) | src[e],
                                      __float_as_int(ef[e]));
        }
    }
}

// Block (512 thr) per superbucket: stage window records in LDS, 256-counter
// histogram + two-level scan, compact in place at exact per-node positions.
// Final records carry PRE-SCALED byte offsets (src*128). Emits off2/end2/invdeg.
__global__ __launch_bounds__(512) void bucket_sort_kernel(
    int2* __restrict__ brec, const int* __restrict__ bcursor,
    int* __restrict__ off2, int* __restrict__ end2,
    float* __restrict__ invdeg, int n_nodes)
{
    __shared__ int2 stage[PADSB];
    __shared__ int  lcnt[SBSZ];
    __shared__ int  lcur[SBSZ];
    __shared__ int  wsum[4];

    const int b   = blockIdx.x;
    const int tid = threadIdx.x;
    const int w0  = b * PADSB;
    int cnt = bcursor[b] - w0;
    if (cnt > PADSB) cnt = PADSB;

    if (tid < SBSZ) lcnt[tid] = 0;
    __syncthreads();

    for (int i = tid; i < cnt; i += 512) {
        const int2 r = brec[w0 + i];
        stage[i] = r;
        atomicAdd(&lcnt[r.x >> 17], 1);
    }
    __syncthreads();

    int v = 0, c = 0;
    if (tid < SBSZ) {
        c = lcnt[tid];
        v = c;
        for (int d = 1; d < 64; d <<= 1) {
            int t = __shfl_up(v, d, 64);
            if ((tid & 63) >= d) v += t;
        }
        if ((tid & 63) == 63) wsum[tid >> 6] = v;
    }
    __syncthreads();
    if (tid == 0) {
        int a = 0;
#pragma unroll
        for (int i = 0; i < 4; ++i) { int t = wsum[i]; wsum[i] = a; a += t; }
    }
    __syncthreads();
    if (tid < SBSZ) {
        const int excl = wsum[tid >> 6] + (v - c);
        lcur[tid] = excl;
        const int node = (b << SBSHIFT) + tid;
        if (node < n_nodes) {
            off2[node]   = w0 + excl;
            end2[node]   = w0 + excl + c;
            invdeg[node] = 1.0f / fmaxf((float)c, 1.0f);
        }
    }
    __syncthreads();

    for (int i = tid; i < cnt; i += 512) {
        const int2 r   = stage[i];
        const int  pos = atomicAdd(&lcur[r.x >> 17], 1);
        brec[w0 + pos] = make_int2((r.x & 0x1FFFF) << 7, r.y);  // byte offset
    }
}

__device__ __forceinline__ unsigned bf16_rne(float f)
{
    unsigned u = __float_as_uint(f);
    return (u + 0x7FFFu + ((u >> 16) & 1u)) >> 16;
}

// RNE-convert fp32 array to packed bf16 (8 elems / thread).
__global__ __launch_bounds__(256) void f32_to_bf16_kernel(
    const float* __restrict__ x, unsigned short* __restrict__ y, int n8)
{
    const int i = blockIdx.x * 256 + threadIdx.x;
    if (i >= n8) return;
    const float4 a = ((const float4*)x)[2 * i];
    const float4 b = ((const float4*)x)[2 * i + 1];
    uint4 o;
    o.x = bf16_rne(a.x) | (bf16_rne(a.y) << 16);
    o.y = bf16_rne(a.z) | (bf16_rne(a.w) << 16);
    o.z = bf16_rne(b.x) | (bf16_rne(b.y) << 16);
    o.w = bf16_rne(b.z) | (bf16_rne(b.w) << 16);
    ((uint4*)y)[i] = o;
}

// TWO nodes per wave: n = lane>>5 selects the node, within 32 lanes
// g = 0..3 edge slots x q = 0..7 feature octets, 2 slots unrolled
// (8 edges/node in flight). rec.x = byte offset. 2-stage shfl reduce.
__global__ __launch_bounds__(256) void agg_kernel(
    const unsigned short* __restrict__ hb, const int2* __restrict__ rec,
    const int* __restrict__ off, const int* __restrict__ end,
    const float* __restrict__ invdeg, float* __restrict__ s, int n_nodes)
{
    const int wid  = (blockIdx.x * 256 + threadIdx.x) >> 6;
    const int lane = threadIdx.x & 63;
    const int n    = lane >> 5;        // node select within wave
    const int r    = lane & 31;
    const int g    = r >> 3;           // 0..3 edge slot
    const int q    = r & 7;            // 0..7 feature octet

    const int  node   = wid * 2 + n;
    const bool active = node < n_nodes;
    const int  e0 = active ? off[node] : 0;
    const int  e1 = active ? end[node] : 0;

    const char* __restrict__ hq = (const char*)hb + q * 16;

    float4 aA0 = make_float4(0.f, 0.f, 0.f, 0.f);
    float4 aA1 = make_float4(0.f, 0.f, 0.f, 0.f);
    float4 aB0 = make_float4(0.f, 0.f, 0.f, 0.f);
    float4 aB1 = make_float4(0.f, 0.f, 0.f, 0.f);

    for (int base = e0; base < e1; base += 8) {
        const int  eA = base + g;
        const int  eB = base + 4 + g;
        const bool vA = eA < e1;
        const bool vB = eB < e1;
        const int2 rA = rec[vA ? eA : e0];
        const int2 rB = rec[vB ? eB : e0];
        const float evA = vA ? __int_as_float(rA.y) : 0.f;
        const float evB = vB ? __int_as_float(rB.y) : 0.f;
        const uint4 xA = *(const uint4*)(hq + rA.x);
        const uint4 xB = *(const uint4*)(hq + rB.x);

        aA0.x = fmaf(__uint_as_float(xA.x << 16),         evA, aA0.x);
        aA0.y = fmaf(__uint_as_float(xA.x & 0xFFFF0000u), evA, aA0.y);
        aA0.z = fmaf(__uint_as_float(xA.y << 16),         evA, aA0.z);
        aA0.w = fmaf(__uint_as_float(xA.y & 0xFFFF0000u), evA, aA0.w);
        aA1.x = fmaf(__uint_as_float(xA.z << 16),         evA, aA1.x);
        aA1.y = fmaf(__uint_as_float(xA.z & 0xFFFF0000u), evA, aA1.y);
        aA1.z = fmaf(__uint_as_float(xA.w << 16),         evA, aA1.z);
        aA1.w = fmaf(__uint_as_float(xA.w & 0xFFFF0000u), evA, aA1.w);

        aB0.x = fmaf(__uint_as_float(xB.x << 16),         evB, aB0.x);
        aB0.y = fmaf(__uint_as_float(xB.x & 0xFFFF0000u), evB, aB0.y);
        aB0.z = fmaf(__uint_as_float(xB.y << 16),         evB, aB0.z);
        aB0.w = fmaf(__uint_as_float(xB.y & 0xFFFF0000u), evB, aB0.w);
        aB1.x = fmaf(__uint_as_float(xB.z << 16),         evB, aB1.x);
        aB1.y = fmaf(__uint_as_float(xB.z & 0xFFFF0000u), evB, aB1.y);
        aB1.z = fmaf(__uint_as_float(xB.w << 16),         evB, aB1.z);
        aB1.w = fmaf(__uint_as_float(xB.w & 0xFFFF0000u), evB, aB1.w);
    }

    float4 a0 = make_float4(aA0.x + aB0.x, aA0.y + aB0.y,
                            aA0.z + aB0.z, aA0.w + aB0.w);
    float4 a1 = make_float4(aA1.x + aB1.x, aA1.y + aB1.y,
                            aA1.z + aB1.z, aA1.w + aB1.w);

#pragma unroll
    for (int m = 8; m <= 16; m <<= 1) {
        a0.x += __shfl_xor(a0.x, m); a0.y += __shfl_xor(a0.y, m);
        a0.z += __shfl_xor(a0.z, m); a0.w += __shfl_xor(a0.w, m);
        a1.x += __shfl_xor(a1.x, m); a1.y += __shfl_xor(a1.y, m);
        a1.z += __shfl_xor(a1.z, m); a1.w += __shfl_xor(a1.w, m);
    }

    if (g == 0 && active) {
        const float id = invdeg[node];
        float* __restrict__ srow = s + (size_t)node * F + q * 8;
        *(float4*)srow = make_float4(a0.x * id, a0.y * id, a0.z * id, a0.w * id);
        *(float4*)(srow + 4) = make_float4(a1.x * id, a1.y * id, a1.z * id, a1.w * id);
    }
}

// Block = 64 nodes x 4 waves. Stage x = [h|s] rows into LDS with coalesced
// loads (h from fp32 or bf16 shadow per IN_BF16), s always fp32. Wave wv
// computes output cols [wv*JT, ...) for all 64 nodes (lane = node), reading
// x from LDS (ds_read_b128) and W via wave-uniform s_load.
// OUT_BF16: write only the bf16 shadow row (next layer's gather + lin input).
template <int OUT, bool RELU, bool IN_BF16, bool OUT_BF16>
__global__ __launch_bounds__(256) void linear_lds_kernel(
    const float* __restrict__ hin_f, const unsigned short* __restrict__ hin_b,
    const float* __restrict__ s,
    const float* __restrict__ W, const float* __restrict__ b,
    float* __restrict__ out, unsigned short* __restrict__ hb_out, int n_nodes)
{
    constexpr int JT  = OUT / 4;   // j-tile per wave: 16 (lin1) / 8 (lin2)
    constexpr int STR = 132;       // row stride in floats (128 + 4, 16B-aligned)
    __shared__ float xin[64 * STR];

    const int tid   = threadIdx.x;
    const int node0 = blockIdx.x * 64;

    if constexpr (IN_BF16) {
        for (int i = tid; i < 512; i += 256) {
            const int ln = i >> 3, c8 = i & 7;
            const int node = node0 + ln;
            uint4 v = make_uint4(0u, 0u, 0u, 0u);
            if (node < n_nodes)
                v = *(const uint4*)&hin_b[(size_t)node * F + c8 * 8];
            float4 lo = make_float4(__uint_as_float(v.x << 16),
                                    __uint_as_float(v.x & 0xFFFF0000u),
                                    __uint_as_float(v.y << 16),
                                    __uint_as_float(v.y & 0xFFFF0000u));
            float4 hi = make_float4(__uint_as_float(v.z << 16),
                                    __uint_as_float(v.z & 0xFFFF0000u),
                                    __uint_as_float(v.w << 16),
                                    __uint_as_float(v.w & 0xFFFF0000u));
            *(float4*)&xin[ln * STR + c8 * 8]     = lo;
            *(float4*)&xin[ln * STR + c8 * 8 + 4] = hi;
        }
    } else {
        for (int i = tid; i < 1024; i += 256) {
            const int ln = i >> 4, c4 = i & 15;
            const int node = node0 + ln;
            float4 v = make_float4(0.f, 0.f, 0.f, 0.f);
            if (node < n_nodes)
                v = *(const float4*)&hin_f[(size_t)node * F + c4 * 4];
            *(float4*)&xin[ln * STR + c4 * 4] = v;
        }
    }
    for (int i = tid; i < 1024; i += 256) {
        const int ln = i >> 4, c4 = i & 15;
        const int node = node0 + ln;
        float4 v = make_float4(0.f, 0.f, 0.f, 0.f);
        if (node < n_nodes) v = *(const float4*)&s[(size_t)node * F + c4 * 4];
        *(float4*)&xin[ln * STR + F + c4 * 4] = v;
    }
    __syncthreads();

    const int lane = tid & 63;
    const int j0   = __builtin_amdgcn_readfirstlane((tid >> 6) * JT);

    float acc[JT];
#pragma unroll
    for (int j = 0; j < JT; ++j) acc[j] = b[j0 + j];

    const float* __restrict__ xrow = &xin[lane * STR];
#pragma unroll 2
    for (int k4 = 0; k4 < 32; ++k4) {
        const float4 xv = *(const float4*)&xrow[k4 * 4];
#pragma unroll
        for (int kk = 0; kk < 4; ++kk) {
            const int   k  = k4 * 4 + kk;
            const float xk = ((const float*)&xv)[kk];
#pragma unroll
            for (int j = 0; j < JT; ++j)
                acc[j] = fmaf(xk, W[k * OUT + j0 + j], acc[j]);
        }
    }

    const int node = node0 + lane;
    if (node < n_nodes) {
#pragma unroll
        for (int j = 0; j < JT; ++j) {
            float v = acc[j];
            if (RELU) v = fmaxf(v, 0.f);
            acc[j] = v;
        }
        if constexpr (OUT_BF16) {
            unsigned* __restrict__ hw =
                (unsigned*)(hb_out + (size_t)node * OUT + j0);
#pragma unroll
            for (int j = 0; j < JT; j += 2)
                hw[j >> 1] = bf16_rne(acc[j]) | (bf16_rne(acc[j + 1]) << 16);
        } else {
#pragma unroll
            for (int j = 0; j < JT; ++j)
                out[(size_t)node * OUT + j0 + j] = acc[j];
        }
    }
}

extern "C" void kernel_launch(void* const* d_in, const int* in_sizes, int n_in,
                              void* d_out, int out_size, void* d_ws, size_t ws_size,
                              hipStream_t stream)
{
    const float* in_feat   = (const float*)d_in[0];
    const float* edge_feat = (const float*)d_in[1];
    const int*   src       = (const int*)d_in[2];
    const int*   dst       = (const int*)d_in[3];
    const float* W1        = (const float*)d_in[4];
    const float* b1        = (const float*)d_in[5];
    const float* W2        = (const float*)d_in[6];
    const float* b2        = (const float*)d_in[7];
    float*       out       = (float*)d_out;

    const int n_nodes = in_sizes[0] / F;
    const int n_edges = in_sizes[2];
    const int nsb     = (n_nodes + SBSZ - 1) >> SBSHIFT;  // 256-node superbuckets

    // workspace layout (4-byte units)
    const int S = 100352;  // >= n_nodes+1, multiple of 256
    int*   wsi     = (int*)d_ws;
    int*   bcursor = wsi;                                 // [nsb]
    int*   off2    = wsi + 1024;                          // [n_nodes]
    int*   end2    = wsi + 1024 + S;                      // [n_nodes]
    float* invdeg  = (float*)(wsi + 1024 + 2 * S);        // [n_nodes]
    int2*  brec    = (int2*)(wsi + 1024 + 3 * S);         // [nsb * PADSB]
    float* s       = (float*)(brec + (size_t)nsb * PADSB);
    unsigned short* hb = (unsigned short*)(s + (size_t)n_nodes * F);

    const int egrid = (n_edges + EPB - 1) / EPB;
    init_cursor_kernel<<<(nsb + 255) / 256, 256, 0, stream>>>(bcursor, nsb);
    multisplit_kernel<<<egrid, TPB, 0, stream>>>(src, dst, edge_feat,
                                                 bcursor, brec, n_edges, nsb);
    bucket_sort_kernel<<<nsb, 512, 0, stream>>>(brec, bcursor, off2, end2,
                                                invdeg, n_nodes);

    const int n8    = (n_nodes * F) >> 3;
    const int cgrid = (n8 + 255) / 256;
    const int agrid = (n_nodes + 7) / 8;     // 2 nodes/wave, 4 waves/block
    const int lgrid = (n_nodes + 63) / 64;

    // ---- layer 1 ----
    f32_to_bf16_kernel<<<cgrid, 256, 0, stream>>>(in_feat, hb, n8);
    agg_kernel<<<agrid, 256, 0, stream>>>(hb, brec, off2, end2, invdeg, s, n_nodes);
    linear_lds_kernel<64, true, false, true><<<lgrid, 256, 0, stream>>>(
        in_feat, nullptr, s, W1, b1, nullptr, hb, n_nodes);

    // ---- layer 2 ----
    agg_kernel<<<agrid, 256, 0, stream>>>(hb, brec, off2, end2, invdeg, s, n_nodes);
    linear_lds_kernel<32, false, true, false><<<lgrid, 256, 0, stream>>>(
        nullptr, hb, s, W2, b2, out, nullptr, n_nodes);
}

// Round 16
// 163.202 us; speedup vs baseline: 1.0638x; 1.0231x over previous
//
#include <hip/hip_runtime.h>
#include <hip/hip_bf16.h>

// ---------------------------------------------------------------------------
// CGNN: 2 layers of { m = h[src]*e ; s = segment_mean(m,dst) ;
//                     [h, h_N] @ W + b (+ relu on layer 1) }
// Round 15: traffic bundle around the (compulsory-bound) gather.
//   - s kept in BF16 end to end (agg packs, linear unpacks in staging)
//   - lin1 h-half staged from hb0 (bf16) -> fp32 in_feat re-read eliminated
//   - agg v7: 16 edges in flight (4 slots) -> one rec->row round trip per
//     average node instead of two
//   - init_cursor folded into the f32->bf16 conversion kernel
//   - superbucket reorder chain (r14) unchanged
// ---------------------------------------------------------------------------

#define F 64
#define EPT 8               // edges per thread in multisplit
#define TPB 1024            // threads per block in multisplit
#define EPB (EPT * TPB)     // edges per block = 8192
#define SBSHIFT 8           // 256 nodes per superbucket
#define SBSZ 256
#define NSBMAX 512
#define PADSB 4864          // padded window per superbucket (mean 4092, +12σ)

__device__ __forceinline__ unsigned bf16_rne(float f)
{
    unsigned u = __float_as_uint(f);
    return (u + 0x7FFFu + ((u >> 16) & 1u)) >> 16;
}

// RNE-convert fp32 array to packed bf16 (8 elems / thread) + init bcursor.
__global__ __launch_bounds__(256) void cvt_init_kernel(
    const float* __restrict__ x, unsigned short* __restrict__ y, int n8,
    int* __restrict__ bcursor, int nsb)
{
    const int i = blockIdx.x * 256 + threadIdx.x;
    if (i < nsb) bcursor[i] = i * PADSB;
    if (i >= n8) return;
    const float4 a = ((const float4*)x)[2 * i];
    const float4 b = ((const float4*)x)[2 * i + 1];
    uint4 o;
    o.x = bf16_rne(a.x) | (bf16_rne(a.y) << 16);
    o.y = bf16_rne(a.z) | (bf16_rne(a.w) << 16);
    o.z = bf16_rne(b.x) | (bf16_rne(b.y) << 16);
    o.w = bf16_rne(b.z) | (bf16_rne(b.w) << 16);
    ((uint4*)y)[i] = o;
}

// Block-local multisplit into padded per-superbucket windows.
// rec.x = (local_dst << 17) | src  (local 8 bits, src 17 bits)
__global__ __launch_bounds__(TPB) void multisplit_kernel(
    const int* __restrict__ src, const int* __restrict__ dst,
    const float* __restrict__ ef, int* __restrict__ bcursor,
    int2* __restrict__ brec, int n_edges, int nsb)
{
    __shared__ int lcnt[NSBMAX];
    __shared__ int lbase[NSBMAX];
    const int tid = threadIdx.x;
    for (int i = tid; i < nsb; i += TPB) lcnt[i] = 0;
    __syncthreads();

    const int e0 = blockIdx.x * EPB + tid;
    int d[EPT], rk[EPT];
#pragma unroll
    for (int k = 0; k < EPT; ++k) {
        const int e = e0 + k * TPB;
        const int dd = (e < n_edges) ? dst[e] : -1;
        d[k]  = dd;
        rk[k] = (dd >= 0) ? atomicAdd(&lcnt[dd >> SBSHIFT], 1) : 0;
    }
    __syncthreads();
    for (int i = tid; i < nsb; i += TPB) {
        const int c = lcnt[i];
        lbase[i] = c ? atomicAdd(&bcursor[i], c) : 0;
    }
    __syncthreads();
#pragma unroll
    for (int k = 0; k < EPT; ++k) {
        const int e = e0 + k * TPB;
        if (e < n_edges) {
            const int dd  = d[k];
            const int bkt = dd >> SBSHIFT;
            const int pos = lbase[bkt] + rk[k];
            if (pos < (bkt + 1) * PADSB)   // overflow guard (never with data)
                brec[pos] = make_int2(((dd & (SBSZ - 1)) << 17) | src[e],
                                      __float_as_int(ef[e]));
        }
    }
}

// Block (512 thr) per superbucket: stage window records in LDS, 256-counter
// histogram + two-level scan, compact in place at exact per-node positions.
// Final records carry PRE-SCALED byte offsets (src*128). Emits off2/end2/invdeg.
__global__ __launch_bounds__(512) void bucket_sort_kernel(
    int2* __restrict__ brec, const int* __restrict__ bcursor,
    int* __restrict__ off2, int* __restrict__ end2,
    float* __restrict__ invdeg, int n_nodes)
{
    __shared__ int2 stage[PADSB];
    __shared__ int  lcnt[SBSZ];
    __shared__ int  lcur[SBSZ];
    __shared__ int  wsum[4];

    const int b   = blockIdx.x;
    const int tid = threadIdx.x;
    const int w0  = b * PADSB;
    int cnt = bcursor[b] - w0;
    if (cnt > PADSB) cnt = PADSB;

    if (tid < SBSZ) lcnt[tid] = 0;
    __syncthreads();

    for (int i = tid; i < cnt; i += 512) {
        const int2 r = brec[w0 + i];
        stage[i] = r;
        atomicAdd(&lcnt[r.x >> 17], 1);
    }
    __syncthreads();

    int v = 0, c = 0;
    if (tid < SBSZ) {
        c = lcnt[tid];
        v = c;
        for (int d = 1; d < 64; d <<= 1) {
            int t = __shfl_up(v, d, 64);
            if ((tid & 63) >= d) v += t;
        }
        if ((tid & 63) == 63) wsum[tid >> 6] = v;
    }
    __syncthreads();
    if (tid == 0) {
        int a = 0;
#pragma unroll
        for (int i = 0; i < 4; ++i) { int t = wsum[i]; wsum[i] = a; a += t; }
    }
    __syncthreads();
    if (tid < SBSZ) {
        const int excl = wsum[tid >> 6] + (v - c);
        lcur[tid] = excl;
        const int node = (b << SBSHIFT) + tid;
        if (node < n_nodes) {
            off2[node]   = w0 + excl;
            end2[node]   = w0 + excl + c;
            invdeg[node] = 1.0f / fmaxf((float)c, 1.0f);
        }
    }
    __syncthreads();

    for (int i = tid; i < cnt; i += 512) {
        const int2 r   = stage[i];
        const int  pos = atomicAdd(&lcur[r.x >> 17], 1);
        brec[w0 + pos] = make_int2((r.x & 0x1FFFF) << 7, r.y);  // byte offset
    }
}

// TWO nodes per wave, 16 edges in flight (4 slots A-D): n = lane>>5 selects
// the node; within 32 lanes g = 0..3 edge slots x q = 0..7 feature octets.
// rec.x = byte offset. One rec->row round trip per 16 edges. 2-stage shfl
// reduce. Result packed to BF16 (one uint4 per q-lane).
__global__ __launch_bounds__(256) void agg_kernel(
    const unsigned short* __restrict__ hb, const int2* __restrict__ rec,
    const int* __restrict__ off, const int* __restrict__ end,
    const float* __restrict__ invdeg, unsigned short* __restrict__ sb,
    int n_nodes)
{
    const int wid  = (blockIdx.x * 256 + threadIdx.x) >> 6;
    const int lane = threadIdx.x & 63;
    const int n    = lane >> 5;        // node select within wave
    const int r    = lane & 31;
    const int g    = r >> 3;           // 0..3 edge slot
    const int q    = r & 7;            // 0..7 feature octet

    const int  node   = wid * 2 + n;
    const bool active = node < n_nodes;
    const int  e0 = active ? off[node] : 0;
    const int  e1 = active ? end[node] : 0;

    const char* __restrict__ hq = (const char*)hb + q * 16;

    float4 aA0 = make_float4(0.f, 0.f, 0.f, 0.f);
    float4 aA1 = make_float4(0.f, 0.f, 0.f, 0.f);
    float4 aB0 = make_float4(0.f, 0.f, 0.f, 0.f);
    float4 aB1 = make_float4(0.f, 0.f, 0.f, 0.f);
    float4 aC0 = make_float4(0.f, 0.f, 0.f, 0.f);
    float4 aC1 = make_float4(0.f, 0.f, 0.f, 0.f);
    float4 aD0 = make_float4(0.f, 0.f, 0.f, 0.f);
    float4 aD1 = make_float4(0.f, 0.f, 0.f, 0.f);

    for (int base = e0; base < e1; base += 16) {
        const int  eA = base + g;
        const int  eB = base + 4 + g;
        const int  eC = base + 8 + g;
        const int  eD = base + 12 + g;
        const bool vA = eA < e1, vB = eB < e1, vC = eC < e1, vD = eD < e1;
        const int2 rA = rec[vA ? eA : e0];
        const int2 rB = rec[vB ? eB : e0];
        const int2 rC = rec[vC ? eC : e0];
        const int2 rD = rec[vD ? eD : e0];
        const float evA = vA ? __int_as_float(rA.y) : 0.f;
        const float evB = vB ? __int_as_float(rB.y) : 0.f;
        const float evC = vC ? __int_as_float(rC.y) : 0.f;
        const float evD = vD ? __int_as_float(rD.y) : 0.f;
        const uint4 xA = *(const uint4*)(hq + rA.x);
        const uint4 xB = *(const uint4*)(hq + rB.x);
        const uint4 xC = *(const uint4*)(hq + rC.x);
        const uint4 xD = *(const uint4*)(hq + rD.x);

#define ACC8(xa, ev, lo, hi)                                         \
        lo.x = fmaf(__uint_as_float(xa.x << 16),         ev, lo.x);  \
        lo.y = fmaf(__uint_as_float(xa.x & 0xFFFF0000u), ev, lo.y);  \
        lo.z = fmaf(__uint_as_float(xa.y << 16),         ev, lo.z);  \
        lo.w = fmaf(__uint_as_float(xa.y & 0xFFFF0000u), ev, lo.w);  \
        hi.x = fmaf(__uint_as_float(xa.z << 16),         ev, hi.x);  \
        hi.y = fmaf(__uint_as_float(xa.z & 0xFFFF0000u), ev, hi.y);  \
        hi.z = fmaf(__uint_as_float(xa.w << 16),         ev, hi.z);  \
        hi.w = fmaf(__uint_as_float(xa.w & 0xFFFF0000u), ev, hi.w);

        ACC8(xA, evA, aA0, aA1)
        ACC8(xB, evB, aB0, aB1)
        ACC8(xC, evC, aC0, aC1)
        ACC8(xD, evD, aD0, aD1)
#undef ACC8
    }

    float4 a0 = make_float4((aA0.x + aB0.x) + (aC0.x + aD0.x),
                            (aA0.y + aB0.y) + (aC0.y + aD0.y),
                            (aA0.z + aB0.z) + (aC0.z + aD0.z),
                            (aA0.w + aB0.w) + (aC0.w + aD0.w));
    float4 a1 = make_float4((aA1.x + aB1.x) + (aC1.x + aD1.x),
                            (aA1.y + aB1.y) + (aC1.y + aD1.y),
                            (aA1.z + aB1.z) + (aC1.z + aD1.z),
                            (aA1.w + aB1.w) + (aC1.w + aD1.w));

    // reduce across g (m = 8, 16) — stays within each 32-lane node half
#pragma unroll
    for (int m = 8; m <= 16; m <<= 1) {
        a0.x += __shfl_xor(a0.x, m); a0.y += __shfl_xor(a0.y, m);
        a0.z += __shfl_xor(a0.z, m); a0.w += __shfl_xor(a0.w, m);
        a1.x += __shfl_xor(a1.x, m); a1.y += __shfl_xor(a1.y, m);
        a1.z += __shfl_xor(a1.z, m); a1.w += __shfl_xor(a1.w, m);
    }

    if (g == 0 && active) {
        const float id = invdeg[node];
        uint4 o;
        o.x = bf16_rne(a0.x * id) | (bf16_rne(a0.y * id) << 16);
        o.y = bf16_rne(a0.z * id) | (bf16_rne(a0.w * id) << 16);
        o.z = bf16_rne(a1.x * id) | (bf16_rne(a1.y * id) << 16);
        o.w = bf16_rne(a1.z * id) | (bf16_rne(a1.w * id) << 16);
        *(uint4*)(sb + (size_t)node * F + q * 8) = o;
    }
}

// Block = 64 nodes x 4 waves. Stage x = [h|s] rows into LDS, both halves
// from packed BF16 (uint4 = 8 bf16, unpacked during staging). Wave wv
// computes output cols [wv*JT, ...) for all 64 nodes (lane = node), reading
// x from LDS (ds_read_b128) and W via wave-uniform s_load.
// OUT_BF16: write only the bf16 shadow row (next layer's gather + lin input).
template <int OUT, bool RELU, bool OUT_BF16>
__global__ __launch_bounds__(256) void linear_lds_kernel(
    const unsigned short* __restrict__ hin_b,
    const unsigned short* __restrict__ sb,
    const float* __restrict__ W, const float* __restrict__ b,
    float* __restrict__ out, unsigned short* __restrict__ hb_out, int n_nodes)
{
    constexpr int JT  = OUT / 4;   // j-tile per wave: 16 (lin1) / 8 (lin2)
    constexpr int STR = 132;       // row stride in floats (128 + 4, 16B-aligned)
    __shared__ float xin[64 * STR];

    const int tid   = threadIdx.x;
    const int node0 = blockIdx.x * 64;

#define STAGE_BF16(srcp, base_off)                                        \
    for (int i = tid; i < 512; i += 256) {                                \
        const int ln = i >> 3, c8 = i & 7;                                \
        const int node = node0 + ln;                                     \
        uint4 v = make_uint4(0u, 0u, 0u, 0u);                             \
        if (node < n_nodes)                                               \
            v = *(const uint4*)&srcp[(size_t)node * F + c8 * 8];          \
        float4 lo = make_float4(__uint_as_float(v.x << 16),               \
                                __uint_as_float(v.x & 0xFFFF0000u),       \
                                __uint_as_float(v.y << 16),               \
                                __uint_as_float(v.y & 0xFFFF0000u));      \
        float4 hi = make_float4(__uint_as_float(v.z << 16),               \
                                __uint_as_float(v.z & 0xFFFF0000u),       \
                                __uint_as_float(v.w << 16),               \
                                __uint_as_float(v.w & 0xFFFF0000u));      \
        *(float4*)&xin[ln * STR + (base_off) + c8 * 8]     = lo;          \
        *(float4*)&xin[ln * STR + (base_off) + c8 * 8 + 4] = hi;          \
    }

    STAGE_BF16(hin_b, 0)   // h-half
    STAGE_BF16(sb,    F)   // s-half
#undef STAGE_BF16
    __syncthreads();

    const int lane = tid & 63;
    const int j0   = __builtin_amdgcn_readfirstlane((tid >> 6) * JT);

    float acc[JT];
#pragma unroll
    for (int j = 0; j < JT; ++j) acc[j] = b[j0 + j];

    const float* __restrict__ xrow = &xin[lane * STR];
#pragma unroll 2
    for (int k4 = 0; k4 < 32; ++k4) {
        const float4 xv = *(const float4*)&xrow[k4 * 4];
#pragma unroll
        for (int kk = 0; kk < 4; ++kk) {
            const int   k  = k4 * 4 + kk;
            const float xk = ((const float*)&xv)[kk];
#pragma unroll
            for (int j = 0; j < JT; ++j)
                acc[j] = fmaf(xk, W[k * OUT + j0 + j], acc[j]);
        }
    }

    const int node = node0 + lane;
    if (node < n_nodes) {
#pragma unroll
        for (int j = 0; j < JT; ++j) {
            float v = acc[j];
            if (RELU) v = fmaxf(v, 0.f);
            acc[j] = v;
        }
        if constexpr (OUT_BF16) {
            unsigned* __restrict__ hw =
                (unsigned*)(hb_out + (size_t)node * OUT + j0);
#pragma unroll
            for (int j = 0; j < JT; j += 2)
                hw[j >> 1] = bf16_rne(acc[j]) | (bf16_rne(acc[j + 1]) << 16);
        } else {
#pragma unroll
            for (int j = 0; j < JT; ++j)
                out[(size_t)node * OUT + j0 + j] = acc[j];
        }
    }
}

extern "C" void kernel_launch(void* const* d_in, const int* in_sizes, int n_in,
                              void* d_out, int out_size, void* d_ws, size_t ws_size,
                              hipStream_t stream)
{
    const float* in_feat   = (const float*)d_in[0];
    const float* edge_feat = (const float*)d_in[1];
    const int*   src       = (const int*)d_in[2];
    const int*   dst       = (const int*)d_in[3];
    const float* W1        = (const float*)d_in[4];
    const float* b1        = (const float*)d_in[5];
    const float* W2        = (const float*)d_in[6];
    const float* b2        = (const float*)d_in[7];
    float*       out       = (float*)d_out;

    const int n_nodes = in_sizes[0] / F;
    const int n_edges = in_sizes[2];
    const int nsb     = (n_nodes + SBSZ - 1) >> SBSHIFT;  // 256-node superbuckets

    // workspace layout (4-byte units)
    const int S = 100352;  // >= n_nodes+1, multiple of 256
    int*   wsi     = (int*)d_ws;
    int*   bcursor = wsi;                                 // [nsb]
    int*   off2    = wsi + 1024;                          // [n_nodes]
    int*   end2    = wsi + 1024 + S;                      // [n_nodes]
    float* invdeg  = (float*)(wsi + 1024 + 2 * S);        // [n_nodes]
    int2*  brec    = (int2*)(wsi + 1024 + 3 * S);         // [nsb * PADSB]
    unsigned short* sb  = (unsigned short*)(brec + (size_t)nsb * PADSB); // s bf16
    unsigned short* hb0 = sb  + (size_t)n_nodes * F;      // in_feat bf16
    unsigned short* hb1 = hb0 + (size_t)n_nodes * F;      // h1 bf16

    const int n8    = (n_nodes * F) >> 3;
    const int cgrid = (n8 + 255) / 256;
    const int egrid = (n_edges + EPB - 1) / EPB;
    const int agrid = (n_nodes + 7) / 8;     // 2 nodes/wave, 4 waves/block
    const int lgrid = (n_nodes + 63) / 64;

    cvt_init_kernel<<<cgrid, 256, 0, stream>>>(in_feat, hb0, n8, bcursor, nsb);
    multisplit_kernel<<<egrid, TPB, 0, stream>>>(src, dst, edge_feat,
                                                 bcursor, brec, n_edges, nsb);
    bucket_sort_kernel<<<nsb, 512, 0, stream>>>(brec, bcursor, off2, end2,
                                                invdeg, n_nodes);

    // ---- layer 1 ----
    agg_kernel<<<agrid, 256, 0, stream>>>(hb0, brec, off2, end2, invdeg, sb, n_nodes);
    linear_lds_kernel<64, true, true><<<lgrid, 256, 0, stream>>>(
        hb0, sb, W1, b1, nullptr, hb1, n_nodes);

    // ---- layer 2 ----
    agg_kernel<<<agrid, 256, 0, stream>>>(hb1, brec, off2, end2, invdeg, sb, n_nodes);
    linear_lds_kernel<32, false, false><<<lgrid, 256, 0, stream>>>(
        hb1, sb, W2, b2, out, nullptr, n_nodes);
}

// Round 17
// 149.982 us; speedup vs baseline: 1.1576x; 1.0881x over previous
//
#include <hip/hip_runtime.h>
#include <hip/hip_bf16.h>

// ---------------------------------------------------------------------------
// CGNN: 2 layers of { m = h[src]*e ; s = segment_mean(m,dst) ;
//                     [h, h_N] @ W + b (+ relu on layer 1) }
// Round 16: GEMM-commute for layer 2 — gather y2 = h1@W2_bot (32-wide, 6.4MB
// table, 64-B rows) instead of h1 (128-B rows): gather demand halves and the
// table nearly fits per-XCD L2.
//   - records carry src*64; agg1 shifts <<1 for its 128-B rows
//   - agg1 back to 8-edge/2-slot (r14 shape; 16-edge was null) + bf16 out
//   - agg_y: 4 nodes/wave (16 lanes: 4 slots x 4 octets), 64-B rows
//   - y2gemm: h1 @ W2[64:128] -> yb2 bf16 ; lin2h: h1 @ W2[0:64] + s2' + b2
//   - superbucket reorder chain (r14) unchanged
// ---------------------------------------------------------------------------

#define F 64
#define EPT 8               // edges per thread in multisplit
#define TPB 1024            // threads per block in multisplit
#define EPB (EPT * TPB)     // edges per block = 8192
#define SBSHIFT 8           // 256 nodes per superbucket
#define SBSZ 256
#define NSBMAX 512
#define PADSB 4864          // padded window per superbucket (mean 4092, +12σ)

__device__ __forceinline__ unsigned bf16_rne(float f)
{
    unsigned u = __float_as_uint(f);
    return (u + 0x7FFFu + ((u >> 16) & 1u)) >> 16;
}

// RNE-convert fp32 array to packed bf16 (8 elems / thread) + init bcursor.
__global__ __launch_bounds__(256) void cvt_init_kernel(
    const float* __restrict__ x, unsigned short* __restrict__ y, int n8,
    int* __restrict__ bcursor, int nsb)
{
    const int i = blockIdx.x * 256 + threadIdx.x;
    if (i < nsb) bcursor[i] = i * PADSB;
    if (i >= n8) return;
    const float4 a = ((const float4*)x)[2 * i];
    const float4 b = ((const float4*)x)[2 * i + 1];
    uint4 o;
    o.x = bf16_rne(a.x) | (bf16_rne(a.y) << 16);
    o.y = bf16_rne(a.z) | (bf16_rne(a.w) << 16);
    o.z = bf16_rne(b.x) | (bf16_rne(b.y) << 16);
    o.w = bf16_rne(b.z) | (bf16_rne(b.w) << 16);
    ((uint4*)y)[i] = o;
}

// Block-local multisplit into padded per-superbucket windows.
// rec.x = (local_dst << 17) | src  (local 8 bits, src 17 bits)
__global__ __launch_bounds__(TPB) void multisplit_kernel(
    const int* __restrict__ src, const int* __restrict__ dst,
    const float* __restrict__ ef, int* __restrict__ bcursor,
    int2* __restrict__ brec, int n_edges, int nsb)
{
    __shared__ int lcnt[NSBMAX];
    __shared__ int lbase[NSBMAX];
    const int tid = threadIdx.x;
    for (int i = tid; i < nsb; i += TPB) lcnt[i] = 0;
    __syncthreads();

    const int e0 = blockIdx.x * EPB + tid;
    int d[EPT], rk[EPT];
#pragma unroll
    for (int k = 0; k < EPT; ++k) {
        const int e = e0 + k * TPB;
        const int dd = (e < n_edges) ? dst[e] : -1;
        d[k]  = dd;
        rk[k] = (dd >= 0) ? atomicAdd(&lcnt[dd >> SBSHIFT], 1) : 0;
    }
    __syncthreads();
    for (int i = tid; i < nsb; i += TPB) {
        const int c = lcnt[i];
        lbase[i] = c ? atomicAdd(&bcursor[i], c) : 0;
    }
    __syncthreads();
#pragma unroll
    for (int k = 0; k < EPT; ++k) {
        const int e = e0 + k * TPB;
        if (e < n_edges) {
            const int dd  = d[k];
            const int bkt = dd >> SBSHIFT;
            const int pos = lbase[bkt] + rk[k];
            if (pos < (bkt + 1) * PADSB)   // overflow guard (never with data)
                brec[pos] = make_int2(((dd & (SBSZ - 1)) << 17) | src[e],
                                      __float_as_int(ef[e]));
        }
    }
}

// Block (512 thr) per superbucket: stage window records in LDS, 256-counter
// histogram + two-level scan, compact in place at exact per-node positions.
// Final records carry src*64 (byte offset of a 64-B row). Emits off2/end2/invdeg.
__global__ __launch_bounds__(512) void bucket_sort_kernel(
    int2* __restrict__ brec, const int* __restrict__ bcursor,
    int* __restrict__ off2, int* __restrict__ end2,
    float* __restrict__ invdeg, int n_nodes)
{
    __shared__ int2 stage[PADSB];
    __shared__ int  lcnt[SBSZ];
    __shared__ int  lcur[SBSZ];
    __shared__ int  wsum[4];

    const int b   = blockIdx.x;
    const int tid = threadIdx.x;
    const int w0  = b * PADSB;
    int cnt = bcursor[b] - w0;
    if (cnt > PADSB) cnt = PADSB;

    if (tid < SBSZ) lcnt[tid] = 0;
    __syncthreads();

    for (int i = tid; i < cnt; i += 512) {
        const int2 r = brec[w0 + i];
        stage[i] = r;
        atomicAdd(&lcnt[r.x >> 17], 1);
    }
    __syncthreads();

    int v = 0, c = 0;
    if (tid < SBSZ) {
        c = lcnt[tid];
        v = c;
        for (int d = 1; d < 64; d <<= 1) {
            int t = __shfl_up(v, d, 64);
            if ((tid & 63) >= d) v += t;
        }
        if ((tid & 63) == 63) wsum[tid >> 6] = v;
    }
    __syncthreads();
    if (tid == 0) {
        int a = 0;
#pragma unroll
        for (int i = 0; i < 4; ++i) { int t = wsum[i]; wsum[i] = a; a += t; }
    }
    __syncthreads();
    if (tid < SBSZ) {
        const int excl = wsum[tid >> 6] + (v - c);
        lcur[tid] = excl;
        const int node = (b << SBSHIFT) + tid;
        if (node < n_nodes) {
            off2[node]   = w0 + excl;
            end2[node]   = w0 + excl + c;
            invdeg[node] = 1.0f / fmaxf((float)c, 1.0f);
        }
    }
    __syncthreads();

    for (int i = tid; i < cnt; i += 512) {
        const int2 r   = stage[i];
        const int  pos = atomicAdd(&lcur[r.x >> 17], 1);
        brec[w0 + pos] = make_int2((r.x & 0x1FFFF) << 6, r.y);  // src*64
    }
}

// agg over 128-B rows (64 bf16 feats): TWO nodes per wave, 8 edges in
// flight (2 slots x 4 g), q = 0..7 feature octets. rec.x = src*64 -> <<1.
// 2-stage shfl reduce (m=8,16). Result packed BF16 (uint4 per q-lane).
__global__ __launch_bounds__(256) void agg_h_kernel(
    const unsigned short* __restrict__ hb, const int2* __restrict__ rec,
    const int* __restrict__ off, const int* __restrict__ end,
    const float* __restrict__ invdeg, unsigned short* __restrict__ sb,
    int n_nodes)
{
    const int wid  = (blockIdx.x * 256 + threadIdx.x) >> 6;
    const int lane = threadIdx.x & 63;
    const int n    = lane >> 5;
    const int r    = lane & 31;
    const int g    = r >> 3;           // 0..3 edge slot
    const int q    = r & 7;            // 0..7 feature octet

    const int  node   = wid * 2 + n;
    const bool active = node < n_nodes;
    const int  e0 = active ? off[node] : 0;
    const int  e1 = active ? end[node] : 0;

    const char* __restrict__ hq = (const char*)hb + q * 16;

    float4 aA0 = make_float4(0.f, 0.f, 0.f, 0.f);
    float4 aA1 = make_float4(0.f, 0.f, 0.f, 0.f);
    float4 aB0 = make_float4(0.f, 0.f, 0.f, 0.f);
    float4 aB1 = make_float4(0.f, 0.f, 0.f, 0.f);

    for (int base = e0; base < e1; base += 8) {
        const int  eA = base + g;
        const int  eB = base + 4 + g;
        const bool vA = eA < e1;
        const bool vB = eB < e1;
        const int2 rA = rec[vA ? eA : e0];
        const int2 rB = rec[vB ? eB : e0];
        const float evA = vA ? __int_as_float(rA.y) : 0.f;
        const float evB = vB ? __int_as_float(rB.y) : 0.f;
        const uint4 xA = *(const uint4*)(hq + ((size_t)(unsigned)rA.x << 1));
        const uint4 xB = *(const uint4*)(hq + ((size_t)(unsigned)rB.x << 1));

#define ACC8(xa, ev, lo, hi)                                         \
        lo.x = fmaf(__uint_as_float(xa.x << 16),         ev, lo.x);  \
        lo.y = fmaf(__uint_as_float(xa.x & 0xFFFF0000u), ev, lo.y);  \
        lo.z = fmaf(__uint_as_float(xa.y << 16),         ev, lo.z);  \
        lo.w = fmaf(__uint_as_float(xa.y & 0xFFFF0000u), ev, lo.w);  \
        hi.x = fmaf(__uint_as_float(xa.z << 16),         ev, hi.x);  \
        hi.y = fmaf(__uint_as_float(xa.z & 0xFFFF0000u), ev, hi.y);  \
        hi.z = fmaf(__uint_as_float(xa.w << 16),         ev, hi.z);  \
        hi.w = fmaf(__uint_as_float(xa.w & 0xFFFF0000u), ev, hi.w);

        ACC8(xA, evA, aA0, aA1)
        ACC8(xB, evB, aB0, aB1)
    }

    float4 a0 = make_float4(aA0.x + aB0.x, aA0.y + aB0.y,
                            aA0.z + aB0.z, aA0.w + aB0.w);
    float4 a1 = make_float4(aA1.x + aB1.x, aA1.y + aB1.y,
                            aA1.z + aB1.z, aA1.w + aB1.w);

#pragma unroll
    for (int m = 8; m <= 16; m <<= 1) {
        a0.x += __shfl_xor(a0.x, m); a0.y += __shfl_xor(a0.y, m);
        a0.z += __shfl_xor(a0.z, m); a0.w += __shfl_xor(a0.w, m);
        a1.x += __shfl_xor(a1.x, m); a1.y += __shfl_xor(a1.y, m);
        a1.z += __shfl_xor(a1.z, m); a1.w += __shfl_xor(a1.w, m);
    }

    if (g == 0 && active) {
        const float id = invdeg[node];
        uint4 o;
        o.x = bf16_rne(a0.x * id) | (bf16_rne(a0.y * id) << 16);
        o.y = bf16_rne(a0.z * id) | (bf16_rne(a0.w * id) << 16);
        o.z = bf16_rne(a1.x * id) | (bf16_rne(a1.y * id) << 16);
        o.w = bf16_rne(a1.z * id) | (bf16_rne(a1.w * id) << 16);
        *(uint4*)(sb + (size_t)node * F + q * 8) = o;
    }
}

// agg over 64-B rows (32 bf16 feats): FOUR nodes per wave (16 lanes each:
// g = 0..3 edge slots x q = 0..3 octets), 8 edges in flight per node.
// rec.x = src*64 = exact byte offset. 2-stage shfl reduce (m=4,8).
__global__ __launch_bounds__(256) void agg_y_kernel(
    const unsigned short* __restrict__ yb, const int2* __restrict__ rec,
    const int* __restrict__ off, const int* __restrict__ end,
    const float* __restrict__ invdeg, unsigned short* __restrict__ s2b,
    int n_nodes)
{
    const int wid  = (blockIdx.x * 256 + threadIdx.x) >> 6;
    const int lane = threadIdx.x & 63;
    const int n    = lane >> 4;        // 0..3 node select
    const int r    = lane & 15;
    const int g    = r >> 2;           // 0..3 edge slot
    const int q    = r & 3;            // 0..3 feature octet

    const int  node   = wid * 4 + n;
    const bool active = node < n_nodes;
    const int  e0 = active ? off[node] : 0;
    const int  e1 = active ? end[node] : 0;

    const char* __restrict__ hq = (const char*)yb + q * 16;

    float4 aA0 = make_float4(0.f, 0.f, 0.f, 0.f);
    float4 aA1 = make_float4(0.f, 0.f, 0.f, 0.f);
    float4 aB0 = make_float4(0.f, 0.f, 0.f, 0.f);
    float4 aB1 = make_float4(0.f, 0.f, 0.f, 0.f);

    for (int base = e0; base < e1; base += 8) {
        const int  eA = base + g;
        const int  eB = base + 4 + g;
        const bool vA = eA < e1;
        const bool vB = eB < e1;
        const int2 rA = rec[vA ? eA : e0];
        const int2 rB = rec[vB ? eB : e0];
        const float evA = vA ? __int_as_float(rA.y) : 0.f;
        const float evB = vB ? __int_as_float(rB.y) : 0.f;
        const uint4 xA = *(const uint4*)(hq + (size_t)(unsigned)rA.x);
        const uint4 xB = *(const uint4*)(hq + (size_t)(unsigned)rB.x);

        ACC8(xA, evA, aA0, aA1)
        ACC8(xB, evB, aB0, aB1)
    }

    float4 a0 = make_float4(aA0.x + aB0.x, aA0.y + aB0.y,
                            aA0.z + aB0.z, aA0.w + aB0.w);
    float4 a1 = make_float4(aA1.x + aB1.x, aA1.y + aB1.y,
                            aA1.z + aB1.z, aA1.w + aB1.w);

#pragma unroll
    for (int m = 4; m <= 8; m <<= 1) {
        a0.x += __shfl_xor(a0.x, m); a0.y += __shfl_xor(a0.y, m);
        a0.z += __shfl_xor(a0.z, m); a0.w += __shfl_xor(a0.w, m);
        a1.x += __shfl_xor(a1.x, m); a1.y += __shfl_xor(a1.y, m);
        a1.z += __shfl_xor(a1.z, m); a1.w += __shfl_xor(a1.w, m);
    }
#undef ACC8

    if (g == 0 && active) {
        const float id = invdeg[node];
        uint4 o;
        o.x = bf16_rne(a0.x * id) | (bf16_rne(a0.y * id) << 16);
        o.y = bf16_rne(a0.z * id) | (bf16_rne(a0.w * id) << 16);
        o.z = bf16_rne(a1.x * id) | (bf16_rne(a1.y * id) << 16);
        o.w = bf16_rne(a1.z * id) | (bf16_rne(a1.w * id) << 16);
        *(uint4*)(s2b + (size_t)node * 32 + q * 8) = o;
    }
}

// Layer-1 linear (unchanged r15 structure): x = [h|s] both 64-wide bf16,
// staged to LDS; 4 waves split OUT cols; W via wave-uniform s_load.
template <int OUT, bool RELU, bool OUT_BF16>
__global__ __launch_bounds__(256) void linear_lds_kernel(
    const unsigned short* __restrict__ hin_b,
    const unsigned short* __restrict__ sb,
    const float* __restrict__ W, const float* __restrict__ b,
    float* __restrict__ out, unsigned short* __restrict__ hb_out, int n_nodes)
{
    constexpr int JT  = OUT / 4;
    constexpr int STR = 132;
    __shared__ float xin[64 * STR];

    const int tid   = threadIdx.x;
    const int node0 = blockIdx.x * 64;

#define STAGE_BF16(srcp, base_off, width)                                 \
    for (int i = tid; i < 64 * ((width) / 8); i += 256) {                 \
        const int ln = i / ((width) / 8), c8 = i % ((width) / 8);         \
        const int node = node0 + ln;                                      \
        uint4 v = make_uint4(0u, 0u, 0u, 0u);                             \
        if (node < n_nodes)                                               \
            v = *(const uint4*)&srcp[(size_t)node * (width) + c8 * 8];    \
        float4 lo = make_float4(__uint_as_float(v.x << 16),               \
                                __uint_as_float(v.x & 0xFFFF0000u),       \
                                __uint_as_float(v.y << 16),               \
                                __uint_as_float(v.y & 0xFFFF0000u));      \
        float4 hi = make_float4(__uint_as_float(v.z << 16),               \
                                __uint_as_float(v.z & 0xFFFF0000u),       \
                                __uint_as_float(v.w << 16),               \
                                __uint_as_float(v.w & 0xFFFF0000u));      \
        *(float4*)&xin[ln * STR + (base_off) + c8 * 8]     = lo;          \
        *(float4*)&xin[ln * STR + (base_off) + c8 * 8 + 4] = hi;          \
    }

    STAGE_BF16(hin_b, 0, 64)
    STAGE_BF16(sb,    F, 64)
    __syncthreads();

    const int lane = tid & 63;
    const int j0   = __builtin_amdgcn_readfirstlane((tid >> 6) * JT);

    float acc[JT];
#pragma unroll
    for (int j = 0; j < JT; ++j) acc[j] = b[j0 + j];

    const float* __restrict__ xrow = &xin[lane * STR];
#pragma unroll 2
    for (int k4 = 0; k4 < 32; ++k4) {
        const float4 xv = *(const float4*)&xrow[k4 * 4];
#pragma unroll
        for (int kk = 0; kk < 4; ++kk) {
            const int   k  = k4 * 4 + kk;
            const float xk = ((const float*)&xv)[kk];
#pragma unroll
            for (int j = 0; j < JT; ++j)
                acc[j] = fmaf(xk, W[k * OUT + j0 + j], acc[j]);
        }
    }

    const int node = node0 + lane;
    if (node < n_nodes) {
#pragma unroll
        for (int j = 0; j < JT; ++j) {
            float v = acc[j];
            if (RELU) v = fmaxf(v, 0.f);
            acc[j] = v;
        }
        if constexpr (OUT_BF16) {
            unsigned* __restrict__ hw =
                (unsigned*)(hb_out + (size_t)node * OUT + j0);
#pragma unroll
            for (int j = 0; j < JT; j += 2)
                hw[j >> 1] = bf16_rne(acc[j]) | (bf16_rne(acc[j + 1]) << 16);
        } else {
#pragma unroll
            for (int j = 0; j < JT; ++j)
                out[(size_t)node * OUT + j0 + j] = acc[j];
        }
    }
}

// y2 = h1 @ W2_bot  ([100K,64] x [64,32] -> bf16). x staged 64-wide.
__global__ __launch_bounds__(256) void y2gemm_kernel(
    const unsigned short* __restrict__ hin_b, const float* __restrict__ Wb,
    unsigned short* __restrict__ yb2, int n_nodes)
{
    constexpr int STR = 68;
    __shared__ float xin[64 * STR];
    const int tid   = threadIdx.x;
    const int node0 = blockIdx.x * 64;

    STAGE_BF16(hin_b, 0, 64)
    __syncthreads();

    const int lane = tid & 63;
    const int j0   = __builtin_amdgcn_readfirstlane((tid >> 6) * 8);

    float acc[8];
#pragma unroll
    for (int j = 0; j < 8; ++j) acc[j] = 0.f;

    const float* __restrict__ xrow = &xin[lane * STR];
#pragma unroll 2
    for (int k4 = 0; k4 < 16; ++k4) {
        const float4 xv = *(const float4*)&xrow[k4 * 4];
#pragma unroll
        for (int kk = 0; kk < 4; ++kk) {
            const int   k  = k4 * 4 + kk;
            const float xk = ((const float*)&xv)[kk];
#pragma unroll
            for (int j = 0; j < 8; ++j)
                acc[j] = fmaf(xk, Wb[k * 32 + j0 + j], acc[j]);
        }
    }

    const int node = node0 + lane;
    if (node < n_nodes) {
        unsigned* __restrict__ hw = (unsigned*)(yb2 + (size_t)node * 32 + j0);
#pragma unroll
        for (int j = 0; j < 8; j += 2)
            hw[j >> 1] = bf16_rne(acc[j]) | (bf16_rne(acc[j + 1]) << 16);
    }
}

// out = h1 @ W2_top + s2' + b2   (x = h1 64-wide; s2' 32-wide, staged)
__global__ __launch_bounds__(256) void lin2h_kernel(
    const unsigned short* __restrict__ hin_b,
    const unsigned short* __restrict__ s2b,
    const float* __restrict__ Wt, const float* __restrict__ b,
    float* __restrict__ out, int n_nodes)
{
    constexpr int STR = 100;   // 64 h + 32 s + 4 pad (same mod-32 residue as 132)
    __shared__ float xin[64 * STR];
    const int tid   = threadIdx.x;
    const int node0 = blockIdx.x * 64;

    STAGE_BF16(hin_b, 0,  64)
    STAGE_BF16(s2b,   64, 32)
#undef STAGE_BF16
    __syncthreads();

    const int lane = tid & 63;
    const int j0   = __builtin_amdgcn_readfirstlane((tid >> 6) * 8);

    float acc[8];
#pragma unroll
    for (int j = 0; j < 8; ++j) acc[j] = b[j0 + j];

    const float* __restrict__ xrow = &xin[lane * STR];
#pragma unroll 2
    for (int k4 = 0; k4 < 16; ++k4) {
        const float4 xv = *(const float4*)&xrow[k4 * 4];
#pragma unroll
        for (int kk = 0; kk < 4; ++kk) {
            const int   k  = k4 * 4 + kk;
            const float xk = ((const float*)&xv)[kk];
#pragma unroll
            for (int j = 0; j < 8; ++j)
                acc[j] = fmaf(xk, Wt[k * 32 + j0 + j], acc[j]);
        }
    }

    const int node = node0 + lane;
    if (node < n_nodes) {
#pragma unroll
        for (int j = 0; j < 8; ++j)
            out[(size_t)node * 32 + j0 + j] = acc[j] + xrow[64 + j0 + j];
    }
}

extern "C" void kernel_launch(void* const* d_in, const int* in_sizes, int n_in,
                              void* d_out, int out_size, void* d_ws, size_t ws_size,
                              hipStream_t stream)
{
    const float* in_feat   = (const float*)d_in[0];
    const float* edge_feat = (const float*)d_in[1];
    const int*   src       = (const int*)d_in[2];
    const int*   dst       = (const int*)d_in[3];
    const float* W1        = (const float*)d_in[4];
    const float* b1        = (const float*)d_in[5];
    const float* W2        = (const float*)d_in[6];
    const float* b2        = (const float*)d_in[7];
    float*       out       = (float*)d_out;

    const int n_nodes = in_sizes[0] / F;
    const int n_edges = in_sizes[2];
    const int nsb     = (n_nodes + SBSZ - 1) >> SBSHIFT;

    // workspace layout (4-byte units)
    const int S = 100352;
    int*   wsi     = (int*)d_ws;
    int*   bcursor = wsi;                                 // [nsb]
    int*   off2    = wsi + 1024;                          // [n_nodes]
    int*   end2    = wsi + 1024 + S;                      // [n_nodes]
    float* invdeg  = (float*)(wsi + 1024 + 2 * S);        // [n_nodes]
    int2*  brec    = (int2*)(wsi + 1024 + 3 * S);         // [nsb * PADSB]
    unsigned short* sb  = (unsigned short*)(brec + (size_t)nsb * PADSB); // s1 bf16 [n*64]
    unsigned short* hb0 = sb  + (size_t)n_nodes * F;      // in_feat bf16 [n*64]
    unsigned short* hb1 = hb0 + (size_t)n_nodes * F;      // h1 bf16 [n*64]
    unsigned short* yb2 = hb1 + (size_t)n_nodes * F;      // y2 bf16 [n*32]
    unsigned short* s2b = yb2 + (size_t)n_nodes * 32;     // s2' bf16 [n*32]

    const int n8     = (n_nodes * F) >> 3;
    const int cgrid  = (n8 + 255) / 256;
    const int egrid  = (n_edges + EPB - 1) / EPB;
    const int agrid1 = (n_nodes + 7) / 8;     // 2 nodes/wave
    const int agrid2 = (n_nodes + 15) / 16;   // 4 nodes/wave
    const int lgrid  = (n_nodes + 63) / 64;

    cvt_init_kernel<<<cgrid, 256, 0, stream>>>(in_feat, hb0, n8, bcursor, nsb);
    multisplit_kernel<<<egrid, TPB, 0, stream>>>(src, dst, edge_feat,
                                                 bcursor, brec, n_edges, nsb);
    bucket_sort_kernel<<<nsb, 512, 0, stream>>>(brec, bcursor, off2, end2,
                                                invdeg, n_nodes);

    // ---- layer 1 ----
    agg_h_kernel<<<agrid1, 256, 0, stream>>>(hb0, brec, off2, end2, invdeg,
                                             sb, n_nodes);
    linear_lds_kernel<64, true, true><<<lgrid, 256, 0, stream>>>(
        hb0, sb, W1, b1, nullptr, hb1, n_nodes);

    // ---- layer 2 (GEMM-commuted aggregation) ----
    y2gemm_kernel<<<lgrid, 256, 0, stream>>>(hb1, W2 + 64 * 32, yb2, n_nodes);
    agg_y_kernel<<<agrid2, 256, 0, stream>>>(yb2, brec, off2, end2, invdeg,
                                             s2b, n_nodes);
    lin2h_kernel<<<lgrid, 256, 0, stream>>>(hb1, s2b, W2, b2, out, n_nodes);
}